// Round 5
// baseline (173.148 us; speedup 1.0000x reference)
//
#include <hip/hip_runtime.h>
#include <hip/hip_fp16.h>

// LJ reduced units: sigma=1, eps=1, cutoff=2.5
// e_pair = 4*(sr6^2 - sr6) - SHIFT, SHIFT = -0.0163168896
// half  = 0.5*e_pair = 2*(sr6^2 - sr6) + 0.0081584448
__device__ __forceinline__ float half_lj(float r2) {
    float sr2 = 1.0f / r2;
    float sr6 = sr2 * sr2 * sr2;
    return fmaf(2.0f, sr6 * sr6 - sr6, 0.0081584448f);
}

// ---------- Design B: bucketize (read pairs once) ----------
#define SL_SHIFT 14
#define SL_SZ    16384            // atoms per slice -> 64 KB LDS accumulator
#define NS_MAX   16               // fast path requires nslices <= 16
#define CAP      448              // per-slice staging capacity per bin block

__device__ __forceinline__ unsigned pack_rec(int atom, float e) {
    unsigned h = (unsigned)__half_as_ushort(__float2half(e));
    return (h << 16) | ((unsigned)atom & (SL_SZ - 1));
}

// K1: fused energy + slice binning. Block = 256 threads x 2 quads = 512 quads.
// Records compacted per slice in LDS, ranges reserved with 16 global atomics,
// dumped coalesced. Overflow (>CAP, ~12 sigma) appends directly via gcnt.
__global__ __launch_bounds__(256)
void bin_kernel(const int4* __restrict__ pairs4, const float4* __restrict__ dist4,
                unsigned* __restrict__ grec, unsigned* __restrict__ gcnt,
                int npair4, int reg_cap) {
    __shared__ unsigned staged[NS_MAX * CAP];
    __shared__ unsigned cnt[NS_MAX];
    __shared__ unsigned baseg[NS_MAX];
    const int tid = threadIdx.x;
    if (tid < NS_MAX) cnt[tid] = 0;
    __syncthreads();

    unsigned rec[16];
    int sl[16];
    bool v0 = false, v1 = false;

#define LOAD_BATCH(k, vflag)                                                   \
    do {                                                                       \
        int q = (blockIdx.x << 9) + ((k) << 8) + tid;                          \
        vflag = (q < npair4);                                                  \
        if (vflag) {                                                           \
            int4 pA = pairs4[2 * q];                                           \
            int4 pB = pairs4[2 * q + 1];                                       \
            float4 d0 = dist4[3 * q], d1 = dist4[3 * q + 1], d2 = dist4[3 * q + 2]; \
            float e0 = half_lj(fmaf(d0.x, d0.x, fmaf(d0.y, d0.y, d0.z * d0.z))); \
            float e1 = half_lj(fmaf(d0.w, d0.w, fmaf(d1.x, d1.x, d1.y * d1.y))); \
            float e2 = half_lj(fmaf(d1.z, d1.z, fmaf(d1.w, d1.w, d2.x * d2.x))); \
            float e3 = half_lj(fmaf(d2.y, d2.y, fmaf(d2.z, d2.z, d2.w * d2.w))); \
            rec[(k)*8+0] = pack_rec(pA.x, e0); sl[(k)*8+0] = (unsigned)pA.x >> SL_SHIFT; \
            rec[(k)*8+1] = pack_rec(pA.y, e0); sl[(k)*8+1] = (unsigned)pA.y >> SL_SHIFT; \
            rec[(k)*8+2] = pack_rec(pA.z, e1); sl[(k)*8+2] = (unsigned)pA.z >> SL_SHIFT; \
            rec[(k)*8+3] = pack_rec(pA.w, e1); sl[(k)*8+3] = (unsigned)pA.w >> SL_SHIFT; \
            rec[(k)*8+4] = pack_rec(pB.x, e2); sl[(k)*8+4] = (unsigned)pB.x >> SL_SHIFT; \
            rec[(k)*8+5] = pack_rec(pB.y, e2); sl[(k)*8+5] = (unsigned)pB.y >> SL_SHIFT; \
            rec[(k)*8+6] = pack_rec(pB.z, e3); sl[(k)*8+6] = (unsigned)pB.z >> SL_SHIFT; \
            rec[(k)*8+7] = pack_rec(pB.w, e3); sl[(k)*8+7] = (unsigned)pB.w >> SL_SHIFT; \
        }                                                                      \
    } while (0)

    LOAD_BATCH(0, v0);
    LOAD_BATCH(1, v1);
#undef LOAD_BATCH

#pragma unroll
    for (int i = 0; i < 16; ++i) {
        bool valid = (i < 8) ? v0 : v1;
        if (valid) {
            int s = sl[i];
            unsigned pos = atomicAdd(&cnt[s], 1u);
            if (pos < CAP) {
                staged[s * CAP + pos] = rec[i];
            } else {  // ~never: direct global append
                unsigned gi = atomicAdd(&gcnt[s], 1u);
                if (gi < (unsigned)reg_cap) grec[(size_t)s * reg_cap + gi] = rec[i];
            }
        }
    }
    __syncthreads();

    if (tid < NS_MAX) {
        unsigned c = cnt[tid] < CAP ? cnt[tid] : CAP;
        baseg[tid] = atomicAdd(&gcnt[tid], c);
    }
    __syncthreads();

    for (int s = 0; s < NS_MAX; ++s) {
        unsigned c = cnt[s] < CAP ? cnt[s] : CAP;
        unsigned bg = baseg[s];
        for (unsigned i = tid; i < c; i += 256)
            if (bg + i < (unsigned)reg_cap)
                grec[(size_t)s * reg_cap + bg + i] = staged[s * CAP + i];
    }
}

// K1 tail: leftover pairs (npairs % 4), direct global append.
__global__ void bin_tail_kernel(const int* __restrict__ pairs,
                                const float* __restrict__ dist,
                                unsigned* __restrict__ grec,
                                unsigned* __restrict__ gcnt,
                                int start, int npairs, int reg_cap) {
    int i = start + blockIdx.x * 64 + threadIdx.x;
    if (i >= npairs) return;
    float dx = dist[3 * i], dy = dist[3 * i + 1], dz = dist[3 * i + 2];
    float h = half_lj(fmaf(dx, dx, fmaf(dy, dy, dz * dz)));
    int a0 = pairs[2 * i], a1 = pairs[2 * i + 1];
    int s0 = (unsigned)a0 >> SL_SHIFT, s1 = (unsigned)a1 >> SL_SHIFT;
    unsigned g0 = atomicAdd(&gcnt[s0], 1u);
    if (g0 < (unsigned)reg_cap) grec[(size_t)s0 * reg_cap + g0] = pack_rec(a0, h);
    unsigned g1 = atomicAdd(&gcnt[s1], 1u);
    if (g1 < (unsigned)reg_cap) grec[(size_t)s1 * reg_cap + g1] = pack_rec(a1, h);
}

// K2: block (s, c) consumes chunk c of slice s's records; every lane's record
// hits this block's LDS accumulator (no filtering waste). Flush to replica c.
__global__ __launch_bounds__(1024)
void accum_records_kernel(const unsigned* __restrict__ grec,
                          const unsigned* __restrict__ gcnt,
                          float* __restrict__ rep,
                          int reg_cap, int nslices, int CH, int n_pad) {
    __shared__ float lds[SL_SZ];
    const int s = blockIdx.x / CH;
    const int c = blockIdx.x % CH;
    const int tid = threadIdx.x;

    float4* lds4 = (float4*)lds;
    for (int i = tid; i < SL_SZ / 4; i += 1024)
        lds4[i] = make_float4(0.f, 0.f, 0.f, 0.f);
    __syncthreads();

    int ns = (int)gcnt[s];
    if (ns > reg_cap) ns = reg_cap;
    const unsigned* base = grec + (size_t)s * reg_cap;
    int beg = (int)((long long)c * ns / CH);
    int end = (int)((long long)(c + 1) * ns / CH);

    for (int i = beg + tid; i < end; i += 1024) {
        unsigned r = base[i];
        float e = __half2float(__ushort_as_half((unsigned short)(r >> 16)));
        atomicAdd(&lds[r & (SL_SZ - 1)], e);
    }
    __syncthreads();

    float4* rep4 = (float4*)(rep + (size_t)c * n_pad + (size_t)s * SL_SZ);
    for (int i = tid; i < SL_SZ / 4; i += 1024)
        rep4[i] = lds4[i];
}

// K3: out = sum over CH replicas.
__global__ void reduce_reps_kernel(const float* __restrict__ rep,
                                   float* __restrict__ out,
                                   int n_atoms, int n_pad, int B) {
    int i4 = blockIdx.x * blockDim.x + threadIdx.x;
    int n4 = n_atoms / 4;
    if (i4 < n4) {
        float4 sum = make_float4(0.f, 0.f, 0.f, 0.f);
        for (int b = 0; b < B; ++b) {
            float4 v = *(const float4*)(rep + (size_t)b * n_pad + 4 * (size_t)i4);
            sum.x += v.x; sum.y += v.y; sum.z += v.z; sum.w += v.w;
        }
        ((float4*)out)[i4] = sum;
    }
    if (i4 == 0) {
        for (int i = n4 * 4; i < n_atoms; ++i) {
            float sum = 0.f;
            for (int b = 0; b < B; ++b) sum += rep[(size_t)b * n_pad + i];
            out[i] = sum;
        }
    }
}

// ---------- Path B fallback: round-4 slice-scan (measured 125 us) ----------
#define PB_SHIFT 15
#define PB_SZ 32768

__global__ void compute_e8_kernel(const float4* __restrict__ dist4,
                                  uint4* __restrict__ e8, int npair8) {
    int t = blockIdx.x * blockDim.x + threadIdx.x;
    if (t >= npair8) return;
    float4 v0 = dist4[6 * t + 0], v1 = dist4[6 * t + 1], v2 = dist4[6 * t + 2];
    float4 v3 = dist4[6 * t + 3], v4 = dist4[6 * t + 4], v5 = dist4[6 * t + 5];
    float h0 = half_lj(fmaf(v0.x, v0.x, fmaf(v0.y, v0.y, v0.z * v0.z)));
    float h1 = half_lj(fmaf(v0.w, v0.w, fmaf(v1.x, v1.x, v1.y * v1.y)));
    float h2 = half_lj(fmaf(v1.z, v1.z, fmaf(v1.w, v1.w, v2.x * v2.x)));
    float h3 = half_lj(fmaf(v2.y, v2.y, fmaf(v2.z, v2.z, v2.w * v2.w)));
    float h4 = half_lj(fmaf(v3.x, v3.x, fmaf(v3.y, v3.y, v3.z * v3.z)));
    float h5 = half_lj(fmaf(v3.w, v3.w, fmaf(v4.x, v4.x, v4.y * v4.y)));
    float h6 = half_lj(fmaf(v4.z, v4.z, fmaf(v4.w, v4.w, v5.x * v5.x)));
    float h7 = half_lj(fmaf(v5.y, v5.y, fmaf(v5.z, v5.z, v5.w * v5.w)));
    union { __half2 h; unsigned u; } c01, c23, c45, c67;
    c01.h = __floats2half2_rn(h0, h1);
    c23.h = __floats2half2_rn(h2, h3);
    c45.h = __floats2half2_rn(h4, h5);
    c67.h = __floats2half2_rn(h6, h7);
    uint4 o; o.x = c01.u; o.y = c23.u; o.z = c45.u; o.w = c67.u;
    e8[t] = o;
}

__global__ void compute_e_tail_kernel(const float* __restrict__ dist,
                                      __half* __restrict__ eh,
                                      int start, int npairs) {
    int i = start + blockIdx.x * blockDim.x + threadIdx.x;
    if (i >= npairs) return;
    float dx = dist[3 * i], dy = dist[3 * i + 1], dz = dist[3 * i + 2];
    eh[i] = __float2half(half_lj(fmaf(dx, dx, fmaf(dy, dy, dz * dz))));
}

__global__ __launch_bounds__(1024, 1)
void accum_slice_kernel(const int4* __restrict__ pairs4,
                        const uint2* __restrict__ eh2,
                        const int* __restrict__ pairs,
                        const __half* __restrict__ eh,
                        float* __restrict__ rep,
                        int npair4, int npairs, int nslices, int B, int n_pad) {
    __shared__ float lds[PB_SZ];
    int gid = blockIdx.x;
    int s = gid % nslices;
    int b = gid / nslices;
    const int tid = threadIdx.x;
    const int base = s << PB_SHIFT;

    float4* lds4 = (float4*)lds;
    for (int i = tid; i < PB_SZ / 4; i += 1024)
        lds4[i] = make_float4(0.f, 0.f, 0.f, 0.f);
    __syncthreads();

    const int qb = (int)((long long)b * npair4 / B);
    const int qe = (int)((long long)(b + 1) * npair4 / B);

#define CHK(atom, val)                                           \
    do {                                                         \
        int _t = (atom) - base;                                  \
        if ((unsigned)_t < PB_SZ) atomicAdd(&lds[_t], (val));    \
    } while (0)

    for (int q = qb + tid; q < qe; q += 1024) {
        int4 pA = pairs4[2 * q];
        int4 pB = pairs4[2 * q + 1];
        uint2 ue = eh2[q];
        union { unsigned u; __half2 h; } a_, b_;
        a_.u = ue.x; b_.u = ue.y;
        float2 e01 = __half22float2(a_.h);
        float2 e23 = __half22float2(b_.h);
        CHK(pA.x, e01.x); CHK(pA.y, e01.x);
        CHK(pA.z, e01.y); CHK(pA.w, e01.y);
        CHK(pB.x, e23.x); CHK(pB.y, e23.x);
        CHK(pB.z, e23.y); CHK(pB.w, e23.y);
    }
    if (b == 0) {
        for (int i = npair4 * 4 + tid; i < npairs; i += 1024) {
            int a0 = pairs[2 * i], a1 = pairs[2 * i + 1];
            float h = __half2float(eh[i]);
            CHK(a0, h);
            CHK(a1, h);
        }
    }
#undef CHK
    __syncthreads();

    float4* rep4 = (float4*)(rep + (size_t)b * n_pad + (size_t)s * PB_SZ);
    for (int i = tid; i < PB_SZ / 4; i += 1024)
        rep4[i] = lds4[i];
}

// ---------- Path C fallback: direct agent atomics (measured 803 us) ----------
__global__ void lj_vec4_agent_kernel(const int4* __restrict__ pairs4,
                                     const float4* __restrict__ dist4,
                                     float* __restrict__ out, int npair4) {
    int t = blockIdx.x * blockDim.x + threadIdx.x;
    if (t >= npair4) return;
    int4 p01 = pairs4[2 * t];
    int4 p23 = pairs4[2 * t + 1];
    float4 d0 = dist4[3 * t];
    float4 d1 = dist4[3 * t + 1];
    float4 d2 = dist4[3 * t + 2];
    float h0 = half_lj(fmaf(d0.x, d0.x, fmaf(d0.y, d0.y, d0.z * d0.z)));
    float h1 = half_lj(fmaf(d0.w, d0.w, fmaf(d1.x, d1.x, d1.y * d1.y)));
    float h2 = half_lj(fmaf(d1.z, d1.z, fmaf(d1.w, d1.w, d2.x * d2.x)));
    float h3 = half_lj(fmaf(d2.y, d2.y, fmaf(d2.z, d2.z, d2.w * d2.w)));
    unsafeAtomicAdd(&out[p01.x], h0);
    unsafeAtomicAdd(&out[p01.y], h0);
    unsafeAtomicAdd(&out[p01.z], h1);
    unsafeAtomicAdd(&out[p01.w], h1);
    unsafeAtomicAdd(&out[p23.x], h2);
    unsafeAtomicAdd(&out[p23.y], h2);
    unsafeAtomicAdd(&out[p23.z], h3);
    unsafeAtomicAdd(&out[p23.w], h3);
}

__global__ void lj_tail_agent_kernel(const int* __restrict__ pairs,
                                     const float* __restrict__ dist,
                                     float* __restrict__ out,
                                     int start, int npairs) {
    int i = start + blockIdx.x * blockDim.x + threadIdx.x;
    if (i >= npairs) return;
    float dx = dist[3 * i], dy = dist[3 * i + 1], dz = dist[3 * i + 2];
    float h = half_lj(fmaf(dx, dx, fmaf(dy, dy, dz * dz)));
    unsafeAtomicAdd(&out[pairs[2 * i]], h);
    unsafeAtomicAdd(&out[pairs[2 * i + 1]], h);
}

extern "C" void kernel_launch(void* const* d_in, const int* in_sizes, int n_in,
                              void* d_out, int out_size, void* d_ws, size_t ws_size,
                              hipStream_t stream) {
    const int* pairs = (const int*)d_in[0];      // [P, 2] int32
    const float* dist = (const float*)d_in[1];   // [P, 3] float32
    float* out = (float*)d_out;                  // [n_atoms] float32

    const int n_atoms = out_size;
    const int npairs = in_sizes[0] / 2;
    const int npair4 = npairs / 4;

    // ---- Path A: bucketize ----
    const int nslices = (n_atoms + SL_SZ - 1) >> SL_SHIFT;
    if (nslices >= 1 && nslices <= NS_MAX && npairs > 0) {
        const int n_pad = nslices << SL_SHIFT;
        long long nrec_tot = 2LL * npairs;
        int reg_cap = (int)(nrec_tot / nslices * 105 / 100 + 4096);
        size_t cnt_bytes = 256;
        size_t rec_bytes = (size_t)NS_MAX * (size_t)reg_cap * 4;
        int CH = 32;
        while (CH > 4 &&
               cnt_bytes + rec_bytes + (size_t)CH * (size_t)n_pad * 4 > ws_size)
            CH >>= 1;
        size_t need = cnt_bytes + rec_bytes + (size_t)CH * (size_t)n_pad * 4;
        if (need <= ws_size) {
            unsigned* gcnt = (unsigned*)d_ws;
            unsigned* grec = (unsigned*)((char*)d_ws + cnt_bytes);
            float* rep = (float*)((char*)d_ws + cnt_bytes + rec_bytes);

            hipMemsetAsync(gcnt, 0, cnt_bytes, stream);

            int nb = (npair4 + 511) / 512;
            if (nb > 0)
                bin_kernel<<<nb, 256, 0, stream>>>(
                    (const int4*)pairs, (const float4*)dist, grec, gcnt,
                    npair4, reg_cap);
            if (npair4 * 4 < npairs)
                bin_tail_kernel<<<1, 64, 0, stream>>>(pairs, dist, grec, gcnt,
                                                      npair4 * 4, npairs, reg_cap);

            accum_records_kernel<<<nslices * CH, 1024, 0, stream>>>(
                grec, gcnt, rep, reg_cap, nslices, CH, n_pad);

            int n4 = n_atoms / 4;
            int grid = (n4 + 255) / 256;
            if (grid == 0) grid = 1;
            reduce_reps_kernel<<<grid, 256, 0, stream>>>(rep, out, n_atoms,
                                                         n_pad, CH);
            return;
        }
    }

    // ---- Path B: round-4 slice-scan ----
    {
        const int nsl = (n_atoms + PB_SZ - 1) >> PB_SHIFT;
        const int n_pad = nsl << PB_SHIFT;
        const size_t e_elems = (size_t)((npairs + 7) / 8) * 8;
        const size_t e_bytes = e_elems * sizeof(__half);
        int B = 32;
        while (B > 8 && e_bytes + (size_t)B * n_pad * sizeof(float) > ws_size)
            B >>= 1;
        if (e_bytes + (size_t)B * n_pad * sizeof(float) <= ws_size) {
            __half* eh = (__half*)d_ws;
            float* rep = (float*)((char*)d_ws + e_bytes);
            int npair8 = npairs / 8;
            if (npair8 > 0)
                compute_e8_kernel<<<(npair8 + 255) / 256, 256, 0, stream>>>(
                    (const float4*)dist, (uint4*)eh, npair8);
            if (npair8 * 8 < npairs)
                compute_e_tail_kernel<<<1, 64, 0, stream>>>(dist, eh,
                                                            npair8 * 8, npairs);
            accum_slice_kernel<<<nsl * B, 1024, 0, stream>>>(
                (const int4*)pairs, (const uint2*)eh, pairs, eh, rep,
                npair4, npairs, nsl, B, n_pad);
            int n4 = n_atoms / 4;
            int grid = (n4 + 255) / 256;
            if (grid == 0) grid = 1;
            reduce_reps_kernel<<<grid, 256, 0, stream>>>(rep, out, n_atoms,
                                                         n_pad, B);
            return;
        }
    }

    // ---- Path C: direct atomics ----
    hipMemsetAsync(d_out, 0, (size_t)out_size * sizeof(float), stream);
    if (npair4 > 0)
        lj_vec4_agent_kernel<<<(npair4 + 255) / 256, 256, 0, stream>>>(
            (const int4*)pairs, (const float4*)dist, out, npair4);
    if (npair4 * 4 < npairs)
        lj_tail_agent_kernel<<<1, 64, 0, stream>>>(pairs, dist, out,
                                                   npair4 * 4, npairs);
}

// Round 6
// 161.882 us; speedup vs baseline: 1.0696x; 1.0696x over previous
//
#include <hip/hip_runtime.h>
#include <hip/hip_fp16.h>

// LJ reduced units: sigma=1, eps=1, cutoff=2.5
// e_pair = 4*(sr6^2 - sr6) - SHIFT, SHIFT = -0.0163168896
// half  = 0.5*e_pair = 2*(sr6^2 - sr6) + 0.0081584448
__device__ __forceinline__ float half_lj(float r2) {
    float sr2 = 1.0f / r2;
    float sr6 = sr2 * sr2 * sr2;
    return fmaf(2.0f, sr6 * sr6 - sr6, 0.0081584448f);
}

// ---------- Path A: bucketize (read pairs once) ----------
#define SL_SHIFT 14
#define SL_SZ    16384            // atoms per slice -> 64 KB LDS accumulator
#define NS_MAX   16               // fast path requires nslices <= 16
#define CAP      640              // per-slice staging cap per bin block (mean 512 + ~6 sigma)

__device__ __forceinline__ unsigned pack_rec(int atom, float e) {
    unsigned h = (unsigned)__half_as_ushort(__float2half(e));
    return (h << 16) | ((unsigned)atom & (SL_SZ - 1));
}

// K1: fused energy + slice binning. Block = 256 threads x 4 quad-batches
// = 1024 quads = 8192 records. Records compacted per slice in LDS, ranges
// reserved with 16 global atomics, dumped coalesced (~2.5KB/slice).
__global__ __launch_bounds__(256)
void bin_kernel(const int4* __restrict__ pairs4, const float4* __restrict__ dist4,
                unsigned* __restrict__ grec, unsigned* __restrict__ gcnt,
                int npair4, int reg_cap) {
    __shared__ unsigned staged[NS_MAX * CAP];   // 40 KB
    __shared__ unsigned cnt[NS_MAX];
    __shared__ unsigned baseg[NS_MAX];
    const int tid = threadIdx.x;
    if (tid < NS_MAX) cnt[tid] = 0;
    __syncthreads();

#define STAGE(atom, ev)                                                        \
    do {                                                                       \
        int _a = (atom);                                                       \
        int _s = (unsigned)_a >> SL_SHIFT;                                     \
        unsigned _r = pack_rec(_a, (ev));                                      \
        unsigned _pos = atomicAdd(&cnt[_s], 1u);                               \
        if (_pos < CAP) {                                                      \
            staged[_s * CAP + _pos] = _r;                                      \
        } else {                                                               \
            unsigned _gi = atomicAdd(&gcnt[_s], 1u);                           \
            if (_gi < (unsigned)reg_cap) grec[(size_t)_s * reg_cap + _gi] = _r;\
        }                                                                      \
    } while (0)

    for (int k = 0; k < 4; ++k) {
        int q = (blockIdx.x << 10) + (k << 8) + tid;
        if (q < npair4) {
            int4 pA = pairs4[2 * q];
            int4 pB = pairs4[2 * q + 1];
            float4 d0 = dist4[3 * q], d1 = dist4[3 * q + 1], d2 = dist4[3 * q + 2];
            float e0 = half_lj(fmaf(d0.x, d0.x, fmaf(d0.y, d0.y, d0.z * d0.z)));
            float e1 = half_lj(fmaf(d0.w, d0.w, fmaf(d1.x, d1.x, d1.y * d1.y)));
            float e2 = half_lj(fmaf(d1.z, d1.z, fmaf(d1.w, d1.w, d2.x * d2.x)));
            float e3 = half_lj(fmaf(d2.y, d2.y, fmaf(d2.z, d2.z, d2.w * d2.w)));
            STAGE(pA.x, e0); STAGE(pA.y, e0);
            STAGE(pA.z, e1); STAGE(pA.w, e1);
            STAGE(pB.x, e2); STAGE(pB.y, e2);
            STAGE(pB.z, e3); STAGE(pB.w, e3);
        }
    }
#undef STAGE
    __syncthreads();

    if (tid < NS_MAX) {
        unsigned c = cnt[tid] < CAP ? cnt[tid] : CAP;
        baseg[tid] = atomicAdd(&gcnt[tid], c);
    }
    __syncthreads();

    for (int s = 0; s < NS_MAX; ++s) {
        unsigned c = cnt[s] < CAP ? cnt[s] : CAP;
        unsigned bg = baseg[s];
        for (unsigned i = tid; i < c; i += 256)
            if (bg + i < (unsigned)reg_cap)
                grec[(size_t)s * reg_cap + bg + i] = staged[s * CAP + i];
    }
}

// K1 tail: leftover pairs (npairs % 4), direct global append.
__global__ void bin_tail_kernel(const int* __restrict__ pairs,
                                const float* __restrict__ dist,
                                unsigned* __restrict__ grec,
                                unsigned* __restrict__ gcnt,
                                int start, int npairs, int reg_cap) {
    int i = start + blockIdx.x * 64 + threadIdx.x;
    if (i >= npairs) return;
    float dx = dist[3 * i], dy = dist[3 * i + 1], dz = dist[3 * i + 2];
    float h = half_lj(fmaf(dx, dx, fmaf(dy, dy, dz * dz)));
    int a0 = pairs[2 * i], a1 = pairs[2 * i + 1];
    int s0 = (unsigned)a0 >> SL_SHIFT, s1 = (unsigned)a1 >> SL_SHIFT;
    unsigned g0 = atomicAdd(&gcnt[s0], 1u);
    if (g0 < (unsigned)reg_cap) grec[(size_t)s0 * reg_cap + g0] = pack_rec(a0, h);
    unsigned g1 = atomicAdd(&gcnt[s1], 1u);
    if (g1 < (unsigned)reg_cap) grec[(size_t)s1 * reg_cap + g1] = pack_rec(a1, h);
}

// K2: block (s, c) consumes chunk c of slice s's records; every record hits
// this block's 64 KB LDS accumulator. Flush to replica c. 2 blocks/CU.
__global__ __launch_bounds__(1024)
void accum_records_kernel(const unsigned* __restrict__ grec,
                          const unsigned* __restrict__ gcnt,
                          float* __restrict__ rep,
                          int reg_cap, int nslices, int CH, int n_pad) {
    __shared__ float lds[SL_SZ];
    const int s = blockIdx.x / CH;
    const int c = blockIdx.x % CH;
    const int tid = threadIdx.x;

    float4* lds4 = (float4*)lds;
    for (int i = tid; i < SL_SZ / 4; i += 1024)
        lds4[i] = make_float4(0.f, 0.f, 0.f, 0.f);
    __syncthreads();

    int ns = (int)gcnt[s];
    if (ns > reg_cap) ns = reg_cap;
    const unsigned* base = grec + (size_t)s * reg_cap;
    int beg = (int)((long long)c * ns / CH);
    int end = (int)((long long)(c + 1) * ns / CH);

#pragma unroll 4
    for (int i = beg + tid; i < end; i += 1024) {
        unsigned r = base[i];
        float e = __half2float(__ushort_as_half((unsigned short)(r >> 16)));
        atomicAdd(&lds[r & (SL_SZ - 1)], e);
    }
    __syncthreads();

    float4* rep4 = (float4*)(rep + (size_t)c * n_pad + (size_t)s * SL_SZ);
    for (int i = tid; i < SL_SZ / 4; i += 1024)
        rep4[i] = lds4[i];
}

// K3: out = sum over CH replicas.
__global__ void reduce_reps_kernel(const float* __restrict__ rep,
                                   float* __restrict__ out,
                                   int n_atoms, int n_pad, int B) {
    int i4 = blockIdx.x * blockDim.x + threadIdx.x;
    int n4 = n_atoms / 4;
    if (i4 < n4) {
        float4 sum = make_float4(0.f, 0.f, 0.f, 0.f);
        for (int b = 0; b < B; ++b) {
            float4 v = *(const float4*)(rep + (size_t)b * n_pad + 4 * (size_t)i4);
            sum.x += v.x; sum.y += v.y; sum.z += v.z; sum.w += v.w;
        }
        ((float4*)out)[i4] = sum;
    }
    if (i4 == 0) {
        for (int i = n4 * 4; i < n_atoms; ++i) {
            float sum = 0.f;
            for (int b = 0; b < B; ++b) sum += rep[(size_t)b * n_pad + i];
            out[i] = sum;
        }
    }
}

// ---------- Path B fallback: round-4 slice-scan (measured 125 us) ----------
#define PB_SHIFT 15
#define PB_SZ 32768

__global__ void compute_e8_kernel(const float4* __restrict__ dist4,
                                  uint4* __restrict__ e8, int npair8) {
    int t = blockIdx.x * blockDim.x + threadIdx.x;
    if (t >= npair8) return;
    float4 v0 = dist4[6 * t + 0], v1 = dist4[6 * t + 1], v2 = dist4[6 * t + 2];
    float4 v3 = dist4[6 * t + 3], v4 = dist4[6 * t + 4], v5 = dist4[6 * t + 5];
    float h0 = half_lj(fmaf(v0.x, v0.x, fmaf(v0.y, v0.y, v0.z * v0.z)));
    float h1 = half_lj(fmaf(v0.w, v0.w, fmaf(v1.x, v1.x, v1.y * v1.y)));
    float h2 = half_lj(fmaf(v1.z, v1.z, fmaf(v1.w, v1.w, v2.x * v2.x)));
    float h3 = half_lj(fmaf(v2.y, v2.y, fmaf(v2.z, v2.z, v2.w * v2.w)));
    float h4 = half_lj(fmaf(v3.x, v3.x, fmaf(v3.y, v3.y, v3.z * v3.z)));
    float h5 = half_lj(fmaf(v3.w, v3.w, fmaf(v4.x, v4.x, v4.y * v4.y)));
    float h6 = half_lj(fmaf(v4.z, v4.z, fmaf(v4.w, v4.w, v5.x * v5.x)));
    float h7 = half_lj(fmaf(v5.y, v5.y, fmaf(v5.z, v5.z, v5.w * v5.w)));
    union { __half2 h; unsigned u; } c01, c23, c45, c67;
    c01.h = __floats2half2_rn(h0, h1);
    c23.h = __floats2half2_rn(h2, h3);
    c45.h = __floats2half2_rn(h4, h5);
    c67.h = __floats2half2_rn(h6, h7);
    uint4 o; o.x = c01.u; o.y = c23.u; o.z = c45.u; o.w = c67.u;
    e8[t] = o;
}

__global__ void compute_e_tail_kernel(const float* __restrict__ dist,
                                      __half* __restrict__ eh,
                                      int start, int npairs) {
    int i = start + blockIdx.x * blockDim.x + threadIdx.x;
    if (i >= npairs) return;
    float dx = dist[3 * i], dy = dist[3 * i + 1], dz = dist[3 * i + 2];
    eh[i] = __float2half(half_lj(fmaf(dx, dx, fmaf(dy, dy, dz * dz))));
}

__global__ __launch_bounds__(1024, 1)
void accum_slice_kernel(const int4* __restrict__ pairs4,
                        const uint2* __restrict__ eh2,
                        const int* __restrict__ pairs,
                        const __half* __restrict__ eh,
                        float* __restrict__ rep,
                        int npair4, int npairs, int nslices, int B, int n_pad) {
    __shared__ float lds[PB_SZ];
    int gid = blockIdx.x;
    int s = gid % nslices;
    int b = gid / nslices;
    const int tid = threadIdx.x;
    const int base = s << PB_SHIFT;

    float4* lds4 = (float4*)lds;
    for (int i = tid; i < PB_SZ / 4; i += 1024)
        lds4[i] = make_float4(0.f, 0.f, 0.f, 0.f);
    __syncthreads();

    const int qb = (int)((long long)b * npair4 / B);
    const int qe = (int)((long long)(b + 1) * npair4 / B);

#define CHK(atom, val)                                           \
    do {                                                         \
        int _t = (atom) - base;                                  \
        if ((unsigned)_t < PB_SZ) atomicAdd(&lds[_t], (val));    \
    } while (0)

    for (int q = qb + tid; q < qe; q += 1024) {
        int4 pA = pairs4[2 * q];
        int4 pB = pairs4[2 * q + 1];
        uint2 ue = eh2[q];
        union { unsigned u; __half2 h; } a_, b_;
        a_.u = ue.x; b_.u = ue.y;
        float2 e01 = __half22float2(a_.h);
        float2 e23 = __half22float2(b_.h);
        CHK(pA.x, e01.x); CHK(pA.y, e01.x);
        CHK(pA.z, e01.y); CHK(pA.w, e01.y);
        CHK(pB.x, e23.x); CHK(pB.y, e23.x);
        CHK(pB.z, e23.y); CHK(pB.w, e23.y);
    }
    if (b == 0) {
        for (int i = npair4 * 4 + tid; i < npairs; i += 1024) {
            int a0 = pairs[2 * i], a1 = pairs[2 * i + 1];
            float h = __half2float(eh[i]);
            CHK(a0, h);
            CHK(a1, h);
        }
    }
#undef CHK
    __syncthreads();

    float4* rep4 = (float4*)(rep + (size_t)b * n_pad + (size_t)s * PB_SZ);
    for (int i = tid; i < PB_SZ / 4; i += 1024)
        rep4[i] = lds4[i];
}

// ---------- Path C fallback: direct agent atomics (measured 803 us) ----------
__global__ void lj_vec4_agent_kernel(const int4* __restrict__ pairs4,
                                     const float4* __restrict__ dist4,
                                     float* __restrict__ out, int npair4) {
    int t = blockIdx.x * blockDim.x + threadIdx.x;
    if (t >= npair4) return;
    int4 p01 = pairs4[2 * t];
    int4 p23 = pairs4[2 * t + 1];
    float4 d0 = dist4[3 * t];
    float4 d1 = dist4[3 * t + 1];
    float4 d2 = dist4[3 * t + 2];
    float h0 = half_lj(fmaf(d0.x, d0.x, fmaf(d0.y, d0.y, d0.z * d0.z)));
    float h1 = half_lj(fmaf(d0.w, d0.w, fmaf(d1.x, d1.x, d1.y * d1.y)));
    float h2 = half_lj(fmaf(d1.z, d1.z, fmaf(d1.w, d1.w, d2.x * d2.x)));
    float h3 = half_lj(fmaf(d2.y, d2.y, fmaf(d2.z, d2.z, d2.w * d2.w)));
    unsafeAtomicAdd(&out[p01.x], h0);
    unsafeAtomicAdd(&out[p01.y], h0);
    unsafeAtomicAdd(&out[p01.z], h1);
    unsafeAtomicAdd(&out[p01.w], h1);
    unsafeAtomicAdd(&out[p23.x], h2);
    unsafeAtomicAdd(&out[p23.y], h2);
    unsafeAtomicAdd(&out[p23.z], h3);
    unsafeAtomicAdd(&out[p23.w], h3);
}

__global__ void lj_tail_agent_kernel(const int* __restrict__ pairs,
                                     const float* __restrict__ dist,
                                     float* __restrict__ out,
                                     int start, int npairs) {
    int i = start + blockIdx.x * blockDim.x + threadIdx.x;
    if (i >= npairs) return;
    float dx = dist[3 * i], dy = dist[3 * i + 1], dz = dist[3 * i + 2];
    float h = half_lj(fmaf(dx, dx, fmaf(dy, dy, dz * dz)));
    unsafeAtomicAdd(&out[pairs[2 * i]], h);
    unsafeAtomicAdd(&out[pairs[2 * i + 1]], h);
}

extern "C" void kernel_launch(void* const* d_in, const int* in_sizes, int n_in,
                              void* d_out, int out_size, void* d_ws, size_t ws_size,
                              hipStream_t stream) {
    const int* pairs = (const int*)d_in[0];      // [P, 2] int32
    const float* dist = (const float*)d_in[1];   // [P, 3] float32
    float* out = (float*)d_out;                  // [n_atoms] float32

    const int n_atoms = out_size;
    const int npairs = in_sizes[0] / 2;
    const int npair4 = npairs / 4;

    // ---- Path A: bucketize ----
    const int nslices = (n_atoms + SL_SZ - 1) >> SL_SHIFT;
    if (nslices >= 1 && nslices <= NS_MAX && npairs > 0) {
        const int n_pad = nslices << SL_SHIFT;
        // slice counts are multinomial: sigma ~ sqrt(2P/ns) ~ 1K at this size;
        // +16384 is ~16 sigma. (Overflow still safe: dropped into bounds-checked
        // region guarded by reg_cap min with gcnt.)
        int reg_cap = (int)(2LL * npairs / nslices + 16384);
        size_t cnt_bytes = 256;
        size_t rec_bytes = (size_t)NS_MAX * (size_t)reg_cap * 4;
        int CH = 32;
        while (CH > 4 &&
               cnt_bytes + rec_bytes + (size_t)CH * (size_t)n_pad * 4 > ws_size)
            CH >>= 1;
        size_t need = cnt_bytes + rec_bytes + (size_t)CH * (size_t)n_pad * 4;
        if (need <= ws_size) {
            unsigned* gcnt = (unsigned*)d_ws;
            unsigned* grec = (unsigned*)((char*)d_ws + cnt_bytes);
            float* rep = (float*)((char*)d_ws + cnt_bytes + rec_bytes);

            hipMemsetAsync(gcnt, 0, cnt_bytes, stream);

            int nb = (npair4 + 1023) / 1024;
            if (nb > 0)
                bin_kernel<<<nb, 256, 0, stream>>>(
                    (const int4*)pairs, (const float4*)dist, grec, gcnt,
                    npair4, reg_cap);
            if (npair4 * 4 < npairs)
                bin_tail_kernel<<<1, 64, 0, stream>>>(pairs, dist, grec, gcnt,
                                                      npair4 * 4, npairs, reg_cap);

            accum_records_kernel<<<nslices * CH, 1024, 0, stream>>>(
                grec, gcnt, rep, reg_cap, nslices, CH, n_pad);

            int n4 = n_atoms / 4;
            int grid = (n4 + 255) / 256;
            if (grid == 0) grid = 1;
            reduce_reps_kernel<<<grid, 256, 0, stream>>>(rep, out, n_atoms,
                                                         n_pad, CH);
            return;
        }
    }

    // ---- Path B: slice-scan ----
    {
        const int nsl = (n_atoms + PB_SZ - 1) >> PB_SHIFT;
        const int n_pad = nsl << PB_SHIFT;
        const size_t e_elems = (size_t)((npairs + 7) / 8) * 8;
        const size_t e_bytes = e_elems * sizeof(__half);
        int B = 32;
        while (B > 8 && e_bytes + (size_t)B * n_pad * sizeof(float) > ws_size)
            B >>= 1;
        if (e_bytes + (size_t)B * n_pad * sizeof(float) <= ws_size) {
            __half* eh = (__half*)d_ws;
            float* rep = (float*)((char*)d_ws + e_bytes);
            int npair8 = npairs / 8;
            if (npair8 > 0)
                compute_e8_kernel<<<(npair8 + 255) / 256, 256, 0, stream>>>(
                    (const float4*)dist, (uint4*)eh, npair8);
            if (npair8 * 8 < npairs)
                compute_e_tail_kernel<<<1, 64, 0, stream>>>(dist, eh,
                                                            npair8 * 8, npairs);
            accum_slice_kernel<<<nsl * B, 1024, 0, stream>>>(
                (const int4*)pairs, (const uint2*)eh, pairs, eh, rep,
                npair4, npairs, nsl, B, n_pad);
            int n4 = n_atoms / 4;
            int grid = (n4 + 255) / 256;
            if (grid == 0) grid = 1;
            reduce_reps_kernel<<<grid, 256, 0, stream>>>(rep, out, n_atoms,
                                                         n_pad, B);
            return;
        }
    }

    // ---- Path C: direct atomics ----
    hipMemsetAsync(d_out, 0, (size_t)out_size * sizeof(float), stream);
    if (npair4 > 0)
        lj_vec4_agent_kernel<<<(npair4 + 255) / 256, 256, 0, stream>>>(
            (const int4*)pairs, (const float4*)dist, out, npair4);
    if (npair4 * 4 < npairs)
        lj_tail_agent_kernel<<<1, 64, 0, stream>>>(pairs, dist, out,
                                                   npair4 * 4, npairs);
}

// Round 7
// 128.831 us; speedup vs baseline: 1.3440x; 1.2565x over previous
//
#include <hip/hip_runtime.h>
#include <hip/hip_fp16.h>

// LJ reduced units: sigma=1, eps=1, cutoff=2.5
// e_pair = 4*(sr6^2 - sr6) - SHIFT, SHIFT = -0.0163168896
// half  = 0.5*e_pair = 2*(sr6^2 - sr6) + 0.0081584448
__device__ __forceinline__ float half_lj(float r2) {
    float sr2 = 1.0f / r2;
    float sr6 = sr2 * sr2 * sr2;
    return fmaf(2.0f, sr6 * sr6 - sr6, 0.0081584448f);
}

// ---------- Path A: 256-bucket binning + atomic-free wave-exclusive accum ----
// bucket = atom >> 10  (256 buckets of 1024 atoms; requires n_atoms <= 262144)
// slice  = bucket >> 4 (16 slices of 16384 atoms = 64 KB LDS accumulator)
// class  = bucket & 15 (the wave that owns this 1024-atom region in K2)
#define SL_SHIFT 14
#define SL_SZ    16384
#define NS_MAX   16
#define NB       256
#define BCAP     48    // per-bucket staging cap per bin block (mean 32, +2.8 sigma)

__device__ __forceinline__ unsigned pack_rec(int atom, float e) {
    unsigned h = (unsigned)__half_as_ushort(__float2half(e));
    return (h << 16) | ((unsigned)atom & (SL_SZ - 1));   // low 14 bits keep class
}

// K1: fused energy + 256-way binning. Block = 256 threads x 1024 quads = 8192
// records. Staged per bucket in LDS (rtn-atomic positions), 256 global rtn-
// atomics reserve ranges, slot-parallel coalesced dump.
__global__ __launch_bounds__(256)
void bin_kernel(const int4* __restrict__ pairs4, const float4* __restrict__ dist4,
                unsigned* __restrict__ grec, unsigned* __restrict__ gcnt,
                int npair4, int bucket_cap) {
    __shared__ unsigned staged[NB * BCAP];   // 48 KB
    __shared__ unsigned cnt[NB];
    __shared__ unsigned gbase[NB];
    const int tid = threadIdx.x;
    cnt[tid] = 0;   // tid < 256 == NB
    __syncthreads();

#define STAGE(atom, ev)                                                        \
    do {                                                                       \
        int _a = (atom);                                                       \
        int _b = (unsigned)_a >> 10;                                           \
        unsigned _r = pack_rec(_a, (ev));                                      \
        unsigned _pos = atomicAdd(&cnt[_b], 1u);                               \
        if (_pos < BCAP) {                                                     \
            staged[_b * BCAP + _pos] = _r;                                     \
        } else {                                                               \
            unsigned _gi = atomicAdd(&gcnt[_b], 1u);                           \
            if (_gi < (unsigned)bucket_cap)                                    \
                grec[(size_t)_b * bucket_cap + _gi] = _r;                      \
        }                                                                      \
    } while (0)

    for (int k = 0; k < 4; ++k) {
        int q = (blockIdx.x << 10) + (k << 8) + tid;
        if (q < npair4) {
            int4 pA = pairs4[2 * q];
            int4 pB = pairs4[2 * q + 1];
            float4 d0 = dist4[3 * q], d1 = dist4[3 * q + 1], d2 = dist4[3 * q + 2];
            float e0 = half_lj(fmaf(d0.x, d0.x, fmaf(d0.y, d0.y, d0.z * d0.z)));
            float e1 = half_lj(fmaf(d0.w, d0.w, fmaf(d1.x, d1.x, d1.y * d1.y)));
            float e2 = half_lj(fmaf(d1.z, d1.z, fmaf(d1.w, d1.w, d2.x * d2.x)));
            float e3 = half_lj(fmaf(d2.y, d2.y, fmaf(d2.z, d2.z, d2.w * d2.w)));
            STAGE(pA.x, e0); STAGE(pA.y, e0);
            STAGE(pA.z, e1); STAGE(pA.w, e1);
            STAGE(pB.x, e2); STAGE(pB.y, e2);
            STAGE(pB.z, e3); STAGE(pB.w, e3);
        }
    }
#undef STAGE
    __syncthreads();

    // one reservation atomic per (block, bucket)
    {
        unsigned c = cnt[tid] < BCAP ? cnt[tid] : BCAP;
        gbase[tid] = atomicAdd(&gcnt[tid], c);
    }
    __syncthreads();

    // slot-parallel dump: NB*BCAP = 12288 slots, 48 iterations
    for (int idx = tid; idx < NB * BCAP; idx += 256) {
        int b = idx / BCAP;
        int i = idx - b * BCAP;
        unsigned c = cnt[b] < BCAP ? cnt[b] : BCAP;
        if ((unsigned)i < c) {
            unsigned pos = gbase[b] + i;
            if (pos < (unsigned)bucket_cap)
                grec[(size_t)b * bucket_cap + pos] = staged[idx];
        }
    }
}

// K1 tail: leftover pairs (npairs % 4), direct global append.
__global__ void bin_tail_kernel(const int* __restrict__ pairs,
                                const float* __restrict__ dist,
                                unsigned* __restrict__ grec,
                                unsigned* __restrict__ gcnt,
                                int start, int npairs, int bucket_cap) {
    int i = start + blockIdx.x * 64 + threadIdx.x;
    if (i >= npairs) return;
    float dx = dist[3 * i], dy = dist[3 * i + 1], dz = dist[3 * i + 2];
    float h = half_lj(fmaf(dx, dx, fmaf(dy, dy, dz * dz)));
    int a0 = pairs[2 * i], a1 = pairs[2 * i + 1];
    int b0 = (unsigned)a0 >> 10, b1 = (unsigned)a1 >> 10;
    unsigned g0 = atomicAdd(&gcnt[b0], 1u);
    if (g0 < (unsigned)bucket_cap) grec[(size_t)b0 * bucket_cap + g0] = pack_rec(a0, h);
    unsigned g1 = atomicAdd(&gcnt[b1], 1u);
    if (g1 < (unsigned)bucket_cap) grec[(size_t)b1 * bucket_cap + g1] = pack_rec(a1, h);
}

// K2: ZERO atomics. Block (s,c), wave w consumes chunk c of bucket s*16+w.
// Wave w exclusively owns acc[w*1024 .. w*1024+1024) -> no cross-wave races.
// Intra-wave same-address races resolved by tag-claim retry: all active lanes
// write their lane id to tag[a] (one write lands per address), read it back;
// the winner does a plain ds read-add-write and retires; losers retry. Wave-
// in-order LDS makes successive RMWs of the same address safe.
__global__ __launch_bounds__(1024)
void accum_tag_kernel(const unsigned* __restrict__ grec,
                      const unsigned* __restrict__ gcnt,
                      float* __restrict__ rep,
                      int bucket_cap, int CH, int n_pad) {
    __shared__ float acc[SL_SZ];            // 64 KB
    __shared__ unsigned char tag[SL_SZ];    // 16 KB (never needs init)
    volatile unsigned char* vtag = tag;
    const int s = blockIdx.x / CH;
    const int c = blockIdx.x % CH;
    const int tid = threadIdx.x;
    const int wave = tid >> 6;
    const int lane = tid & 63;

    float4* acc4 = (float4*)acc;
    for (int i = tid; i < SL_SZ / 4; i += 1024)
        acc4[i] = make_float4(0.f, 0.f, 0.f, 0.f);
    __syncthreads();

    const int b = (s << 4) | wave;
    int M = (int)gcnt[b];
    if (M > bucket_cap) M = bucket_cap;
    const unsigned* base = grec + (size_t)b * bucket_cap;
    const int beg = (int)((long long)c * M / CH);
    const int end = (int)((long long)(c + 1) * M / CH);

    for (int jj = beg; jj < end; jj += 64) {
        int j = jj + lane;
        bool valid = j < end;
        unsigned rec = valid ? base[j] : 0u;
        int a = rec & (SL_SZ - 1);   // class bits [13:10] == wave by construction
        float v = __half2float(__ushort_as_half((unsigned short)(rec >> 16)));
        bool active = valid;
        while (__any(active)) {
            if (active) vtag[a] = (unsigned char)lane;
            if (active && vtag[a] == (unsigned char)lane) {
                acc[a] += v;          // plain ds_read + add + ds_write
                active = false;
            }
        }
    }
    __syncthreads();

    float4* rep4 = (float4*)(rep + (size_t)c * n_pad + (size_t)s * SL_SZ);
    for (int i = tid; i < SL_SZ / 4; i += 1024)
        rep4[i] = acc4[i];
}

// K3: out = sum over CH replicas.
__global__ void reduce_reps_kernel(const float* __restrict__ rep,
                                   float* __restrict__ out,
                                   int n_atoms, int n_pad, int B) {
    int i4 = blockIdx.x * blockDim.x + threadIdx.x;
    int n4 = n_atoms / 4;
    if (i4 < n4) {
        float4 sum = make_float4(0.f, 0.f, 0.f, 0.f);
        for (int b = 0; b < B; ++b) {
            float4 v = *(const float4*)(rep + (size_t)b * n_pad + 4 * (size_t)i4);
            sum.x += v.x; sum.y += v.y; sum.z += v.z; sum.w += v.w;
        }
        ((float4*)out)[i4] = sum;
    }
    if (i4 == 0) {
        for (int i = n4 * 4; i < n_atoms; ++i) {
            float sum = 0.f;
            for (int b = 0; b < B; ++b) sum += rep[(size_t)b * n_pad + i];
            out[i] = sum;
        }
    }
}

// ---------- Path B fallback: slice-scan (measured 125 us) ----------
#define PB_SHIFT 15
#define PB_SZ 32768

__global__ void compute_e8_kernel(const float4* __restrict__ dist4,
                                  uint4* __restrict__ e8, int npair8) {
    int t = blockIdx.x * blockDim.x + threadIdx.x;
    if (t >= npair8) return;
    float4 v0 = dist4[6 * t + 0], v1 = dist4[6 * t + 1], v2 = dist4[6 * t + 2];
    float4 v3 = dist4[6 * t + 3], v4 = dist4[6 * t + 4], v5 = dist4[6 * t + 5];
    float h0 = half_lj(fmaf(v0.x, v0.x, fmaf(v0.y, v0.y, v0.z * v0.z)));
    float h1 = half_lj(fmaf(v0.w, v0.w, fmaf(v1.x, v1.x, v1.y * v1.y)));
    float h2 = half_lj(fmaf(v1.z, v1.z, fmaf(v1.w, v1.w, v2.x * v2.x)));
    float h3 = half_lj(fmaf(v2.y, v2.y, fmaf(v2.z, v2.z, v2.w * v2.w)));
    float h4 = half_lj(fmaf(v3.x, v3.x, fmaf(v3.y, v3.y, v3.z * v3.z)));
    float h5 = half_lj(fmaf(v3.w, v3.w, fmaf(v4.x, v4.x, v4.y * v4.y)));
    float h6 = half_lj(fmaf(v4.z, v4.z, fmaf(v4.w, v4.w, v5.x * v5.x)));
    float h7 = half_lj(fmaf(v5.y, v5.y, fmaf(v5.z, v5.z, v5.w * v5.w)));
    union { __half2 h; unsigned u; } c01, c23, c45, c67;
    c01.h = __floats2half2_rn(h0, h1);
    c23.h = __floats2half2_rn(h2, h3);
    c45.h = __floats2half2_rn(h4, h5);
    c67.h = __floats2half2_rn(h6, h7);
    uint4 o; o.x = c01.u; o.y = c23.u; o.z = c45.u; o.w = c67.u;
    e8[t] = o;
}

__global__ void compute_e_tail_kernel(const float* __restrict__ dist,
                                      __half* __restrict__ eh,
                                      int start, int npairs) {
    int i = start + blockIdx.x * blockDim.x + threadIdx.x;
    if (i >= npairs) return;
    float dx = dist[3 * i], dy = dist[3 * i + 1], dz = dist[3 * i + 2];
    eh[i] = __float2half(half_lj(fmaf(dx, dx, fmaf(dy, dy, dz * dz))));
}

__global__ __launch_bounds__(1024, 1)
void accum_slice_kernel(const int4* __restrict__ pairs4,
                        const uint2* __restrict__ eh2,
                        const int* __restrict__ pairs,
                        const __half* __restrict__ eh,
                        float* __restrict__ rep,
                        int npair4, int npairs, int nslices, int B, int n_pad) {
    __shared__ float lds[PB_SZ];
    int gid = blockIdx.x;
    int s = gid % nslices;
    int b = gid / nslices;
    const int tid = threadIdx.x;
    const int base = s << PB_SHIFT;

    float4* lds4 = (float4*)lds;
    for (int i = tid; i < PB_SZ / 4; i += 1024)
        lds4[i] = make_float4(0.f, 0.f, 0.f, 0.f);
    __syncthreads();

    const int qb = (int)((long long)b * npair4 / B);
    const int qe = (int)((long long)(b + 1) * npair4 / B);

#define CHK(atom, val)                                           \
    do {                                                         \
        int _t = (atom) - base;                                  \
        if ((unsigned)_t < PB_SZ) atomicAdd(&lds[_t], (val));    \
    } while (0)

    for (int q = qb + tid; q < qe; q += 1024) {
        int4 pA = pairs4[2 * q];
        int4 pB = pairs4[2 * q + 1];
        uint2 ue = eh2[q];
        union { unsigned u; __half2 h; } a_, b_;
        a_.u = ue.x; b_.u = ue.y;
        float2 e01 = __half22float2(a_.h);
        float2 e23 = __half22float2(b_.h);
        CHK(pA.x, e01.x); CHK(pA.y, e01.x);
        CHK(pA.z, e01.y); CHK(pA.w, e01.y);
        CHK(pB.x, e23.x); CHK(pB.y, e23.x);
        CHK(pB.z, e23.y); CHK(pB.w, e23.y);
    }
    if (b == 0) {
        for (int i = npair4 * 4 + tid; i < npairs; i += 1024) {
            int a0 = pairs[2 * i], a1 = pairs[2 * i + 1];
            float h = __half2float(eh[i]);
            CHK(a0, h);
            CHK(a1, h);
        }
    }
#undef CHK
    __syncthreads();

    float4* rep4 = (float4*)(rep + (size_t)b * n_pad + (size_t)s * PB_SZ);
    for (int i = tid; i < PB_SZ / 4; i += 1024)
        rep4[i] = lds4[i];
}

// ---------- Path C fallback: direct agent atomics (measured 803 us) ----------
__global__ void lj_vec4_agent_kernel(const int4* __restrict__ pairs4,
                                     const float4* __restrict__ dist4,
                                     float* __restrict__ out, int npair4) {
    int t = blockIdx.x * blockDim.x + threadIdx.x;
    if (t >= npair4) return;
    int4 p01 = pairs4[2 * t];
    int4 p23 = pairs4[2 * t + 1];
    float4 d0 = dist4[3 * t];
    float4 d1 = dist4[3 * t + 1];
    float4 d2 = dist4[3 * t + 2];
    float h0 = half_lj(fmaf(d0.x, d0.x, fmaf(d0.y, d0.y, d0.z * d0.z)));
    float h1 = half_lj(fmaf(d0.w, d0.w, fmaf(d1.x, d1.x, d1.y * d1.y)));
    float h2 = half_lj(fmaf(d1.z, d1.z, fmaf(d1.w, d1.w, d2.x * d2.x)));
    float h3 = half_lj(fmaf(d2.y, d2.y, fmaf(d2.z, d2.z, d2.w * d2.w)));
    unsafeAtomicAdd(&out[p01.x], h0);
    unsafeAtomicAdd(&out[p01.y], h0);
    unsafeAtomicAdd(&out[p01.z], h1);
    unsafeAtomicAdd(&out[p01.w], h1);
    unsafeAtomicAdd(&out[p23.x], h2);
    unsafeAtomicAdd(&out[p23.y], h2);
    unsafeAtomicAdd(&out[p23.z], h3);
    unsafeAtomicAdd(&out[p23.w], h3);
}

__global__ void lj_tail_agent_kernel(const int* __restrict__ pairs,
                                     const float* __restrict__ dist,
                                     float* __restrict__ out,
                                     int start, int npairs) {
    int i = start + blockIdx.x * blockDim.x + threadIdx.x;
    if (i >= npairs) return;
    float dx = dist[3 * i], dy = dist[3 * i + 1], dz = dist[3 * i + 2];
    float h = half_lj(fmaf(dx, dx, fmaf(dy, dy, dz * dz)));
    unsafeAtomicAdd(&out[pairs[2 * i]], h);
    unsafeAtomicAdd(&out[pairs[2 * i + 1]], h);
}

extern "C" void kernel_launch(void* const* d_in, const int* in_sizes, int n_in,
                              void* d_out, int out_size, void* d_ws, size_t ws_size,
                              hipStream_t stream) {
    const int* pairs = (const int*)d_in[0];      // [P, 2] int32
    const float* dist = (const float*)d_in[1];   // [P, 3] float32
    float* out = (float*)d_out;                  // [n_atoms] float32

    const int n_atoms = out_size;
    const int npairs = in_sizes[0] / 2;
    const int npair4 = npairs / 4;

    // ---- Path A: 256-bucket bin + atomic-free accumulate ----
    const int nslices = (n_atoms + SL_SZ - 1) >> SL_SHIFT;
    if (n_atoms <= NB * 1024 && nslices <= NS_MAX && npairs > 0) {
        const int n_pad = nslices << SL_SHIFT;
        // per-bucket mean 2P/256 (=65536 here), sigma ~ 256; +2048 = 8 sigma
        int bucket_cap = (int)(2LL * npairs / NB + 2048);
        size_t cnt_bytes = 4096;
        size_t rec_bytes = (size_t)NB * (size_t)bucket_cap * 4;
        int CH = 32;
        while (CH > 4 &&
               cnt_bytes + rec_bytes + (size_t)CH * (size_t)n_pad * 4 > ws_size)
            CH >>= 1;
        size_t need = cnt_bytes + rec_bytes + (size_t)CH * (size_t)n_pad * 4;
        if (need <= ws_size) {
            unsigned* gcnt = (unsigned*)d_ws;
            unsigned* grec = (unsigned*)((char*)d_ws + cnt_bytes);
            float* rep = (float*)((char*)d_ws + cnt_bytes + rec_bytes);

            hipMemsetAsync(gcnt, 0, NB * sizeof(unsigned), stream);

            int nb = (npair4 + 1023) / 1024;
            if (nb > 0)
                bin_kernel<<<nb, 256, 0, stream>>>(
                    (const int4*)pairs, (const float4*)dist, grec, gcnt,
                    npair4, bucket_cap);
            if (npair4 * 4 < npairs)
                bin_tail_kernel<<<1, 64, 0, stream>>>(pairs, dist, grec, gcnt,
                                                      npair4 * 4, npairs,
                                                      bucket_cap);

            accum_tag_kernel<<<nslices * CH, 1024, 0, stream>>>(
                grec, gcnt, rep, bucket_cap, CH, n_pad);

            int n4 = n_atoms / 4;
            int grid = (n4 + 255) / 256;
            if (grid == 0) grid = 1;
            reduce_reps_kernel<<<grid, 256, 0, stream>>>(rep, out, n_atoms,
                                                         n_pad, CH);
            return;
        }
    }

    // ---- Path B: slice-scan ----
    {
        const int nsl = (n_atoms + PB_SZ - 1) >> PB_SHIFT;
        const int n_pad = nsl << PB_SHIFT;
        const size_t e_elems = (size_t)((npairs + 7) / 8) * 8;
        const size_t e_bytes = e_elems * sizeof(__half);
        int B = 32;
        while (B > 8 && e_bytes + (size_t)B * n_pad * sizeof(float) > ws_size)
            B >>= 1;
        if (e_bytes + (size_t)B * n_pad * sizeof(float) <= ws_size) {
            __half* eh = (__half*)d_ws;
            float* rep = (float*)((char*)d_ws + e_bytes);
            int npair8 = npairs / 8;
            if (npair8 > 0)
                compute_e8_kernel<<<(npair8 + 255) / 256, 256, 0, stream>>>(
                    (const float4*)dist, (uint4*)eh, npair8);
            if (npair8 * 8 < npairs)
                compute_e_tail_kernel<<<1, 64, 0, stream>>>(dist, eh,
                                                            npair8 * 8, npairs);
            accum_slice_kernel<<<nsl * B, 1024, 0, stream>>>(
                (const int4*)pairs, (const uint2*)eh, pairs, eh, rep,
                npair4, npairs, nsl, B, n_pad);
            int n4 = n_atoms / 4;
            int grid = (n4 + 255) / 256;
            if (grid == 0) grid = 1;
            reduce_reps_kernel<<<grid, 256, 0, stream>>>(rep, out, n_atoms,
                                                         n_pad, B);
            return;
        }
    }

    // ---- Path C: direct atomics ----
    hipMemsetAsync(d_out, 0, (size_t)out_size * sizeof(float), stream);
    if (npair4 > 0)
        lj_vec4_agent_kernel<<<(npair4 + 255) / 256, 256, 0, stream>>>(
            (const int4*)pairs, (const float4*)dist, out, npair4);
    if (npair4 * 4 < npairs)
        lj_tail_agent_kernel<<<1, 64, 0, stream>>>(pairs, dist, out,
                                                   npair4 * 4, npairs);
}